// Round 10
// baseline (570.409 us; speedup 1.0000x reference)
//
#include <hip/hip_runtime.h>
#include <hip/hip_bf16.h>
#include <math.h>

// Problem constants
#define BB 2
#define SS 2048
#define DDIM 1024
#define NHEAD 16
#define NSTR 8
#define SDIMC 128
#define NCH 16      // chunks for delta scan
#define CLEN 128    // chunk length
#define EPSV 1e-6f

using bf16 = __hip_bfloat16;
typedef __attribute__((ext_vector_type(8))) __bf16 bf8;
typedef __attribute__((ext_vector_type(4))) float f4;

__device__ __forceinline__ bf16 f2b(float v) { return __float2bfloat16(v); }
__device__ __forceinline__ bf8 ld8(const bf16* p) { return *(const bf8*)p; }
__device__ __forceinline__ f4 MFMA(bf8 a, bf8 b, f4 c) {
  return __builtin_amdgcn_mfma_f32_16x16x32_bf16(a, b, c, 0, 0, 0);
}
__device__ __forceinline__ float sigm(float x) { return 1.0f / (1.0f + expf(-x)); }
__device__ __forceinline__ float fexp2(float x) { return __builtin_amdgcn_exp2f(x); }

// async global->LDS 16B copy (m97 pattern; LDS dest must be uniform + lane*16)
__device__ __forceinline__ void glds16(bf16* l, const bf16* g) {
  __builtin_amdgcn_global_load_lds(
      (const __attribute__((address_space(1))) unsigned int*)g,
      (__attribute__((address_space(3))) unsigned int*)l, 16, 0, 0);
}

// ---------------- f32 -> bf16 weight conversion (all 4 weights, one launch) --
__global__ __launch_bounds__(256) void cvt_all(const float* __restrict__ ipw,
                                               const float* __restrict__ ow,
                                               const float* __restrict__ w1,
                                               const float* __restrict__ w2,
                                               bf16* __restrict__ WIPW,
                                               bf16* __restrict__ WOW,
                                               bf16* __restrict__ W1B,
                                               bf16* __restrict__ W2B) {
  const int S1 = 3 * DDIM * DDIM, S2 = S1 + DDIM * DDIM,
            S3 = S2 + 4 * DDIM * DDIM;
  int i4 = (blockIdx.x * 256 + threadIdx.x) * 4;   // grid covers 12.58M elems
  const float* src;
  bf16* dst;
  int off;
  if (i4 < S1)      { src = ipw; dst = WIPW; off = i4; }
  else if (i4 < S2) { src = ow;  dst = WOW;  off = i4 - S1; }
  else if (i4 < S3) { src = w1;  dst = W1B;  off = i4 - S2; }
  else              { src = w2;  dst = W2B;  off = i4 - S3; }
  float4 v = *(const float4*)(src + off);
  dst[off]     = f2b(v.x);
  dst[off + 1] = f2b(v.y);
  dst[off + 2] = f2b(v.z);
  dst[off + 3] = f2b(v.w);
}

// ---------------- Delta operator: 3-pass chunked affine scan ----------------
__global__ __launch_bounds__(256) void delta_passA(const float* __restrict__ x,
                                                   const float* __restrict__ decay,
                                                   float* __restrict__ SA) {
  int idx = blockIdx.x * 256 + threadIdx.x;      // [b][c][d]
  int d = idx % DDIM;
  int c = (idx / DDIM) % NCH;
  int b = idx / (DDIM * NCH);
  float beta = sigm(decay[d]);
  float omb = 1.0f - beta;
  const float* xp = x + ((size_t)(b * SS + c * CLEN)) * DDIM + d;
  float s = 0.0f;
  for (int j = 0; j < CLEN; j++) {
    float xv = xp[(size_t)j * DDIM];
    s = beta * s + omb * xv;
  }
  SA[idx] = s;
}

__global__ __launch_bounds__(256) void delta_passB(const float* __restrict__ SA,
                                                   const float* __restrict__ decay,
                                                   float* __restrict__ SIN) {
  int idx = blockIdx.x * 256 + threadIdx.x;      // [b][d]
  int d = idx % DDIM;
  int b = idx / DDIM;
  float beta = sigm(decay[d]);
  float p = beta;
  for (int i = 0; i < 7; i++) p *= p;            // beta^128
  float s = 0.0f;
  for (int c = 0; c < NCH; c++) {
    SIN[(b * NCH + c) * DDIM + d] = s;
    s = p * s + SA[(b * NCH + c) * DDIM + d];
  }
}

__global__ __launch_bounds__(256) void delta_passC(const float* __restrict__ x,
                                                   const float* __restrict__ decay,
                                                   const float* __restrict__ SIN,
                                                   float* __restrict__ XD,
                                                   float* __restrict__ SA) {
  int idx = blockIdx.x * 256 + threadIdx.x;      // [b][c][d]
  int d = idx % DDIM;
  int c = (idx / DDIM) % NCH;
  int b = idx / (DDIM * NCH);
  float beta = sigm(decay[d]);
  float omb = 1.0f - beta;
  const float* xp = x + ((size_t)(b * SS + c * CLEN)) * DDIM + d;
  float* xdp = XD + ((size_t)(b * SS + c * CLEN)) * DDIM + d;
  float s = SIN[idx];
  float sum = 0.0f;
  for (int j = 0; j < CLEN; j++) {
    float xv = xp[(size_t)j * DDIM];
    float o = xv - s;
    xdp[(size_t)j * DDIM] = o;
    sum += o;
    s = beta * s + omb * xv;
  }
  SA[idx] = sum;
}

// ---------------- gates (g_res) + sinkhorn ----------------
__global__ __launch_bounds__(1024) void gates_sinkhorn(const float* __restrict__ SA,
                                                       const float* __restrict__ gw,
                                                       const float* __restrict__ gb,
                                                       const float* __restrict__ phi,
                                                       float* __restrict__ gres,
                                                       float* __restrict__ hres) {
  int tid = threadIdx.x;
  int wave = tid >> 6, lane = tid & 63;
  int b = wave >> 3, j = wave & 7;               // 16 waves: (b, gate j)
  float acc = 0.0f;
  for (int d = lane; d < DDIM; d += 64) {
    float xs = 0.0f;
    for (int c = 0; c < NCH; c++) xs += SA[(b * NCH + c) * DDIM + d];
    xs *= (1.0f / (float)SS);
    acc += xs * gw[(2 * NSTR + j) * DDIM + d];
  }
  for (int off = 32; off > 0; off >>= 1) acc += __shfl_down(acc, off);
  if (lane == 0) gres[b * NSTR + j] = sigm(acc + gb[2 * NSTR + j]);
  __syncthreads();
  if (tid == 0) {
    float Km[8][8];
    for (int i = 0; i < 8; i++)
      for (int jj = 0; jj < 8; jj++) Km[i][jj] = expf(phi[i * 8 + jj]);
    for (int it = 0; it < 15; it++) {
      for (int i = 0; i < 8; i++) {
        float rs = 0.0f;
        for (int jj = 0; jj < 8; jj++) rs += Km[i][jj];
        float inv = 1.0f / rs;
        for (int jj = 0; jj < 8; jj++) Km[i][jj] *= inv;
      }
      for (int jj = 0; jj < 8; jj++) {
        float cs = 0.0f;
        for (int i = 0; i < 8; i++) cs += Km[i][jj];
        float inv = 1.0f / cs;
        for (int i = 0; i < 8; i++) Km[i][jj] *= inv;
      }
    }
    for (int i = 0; i < 8; i++)
      for (int jj = 0; jj < 8; jj++) hres[i * 8 + jj] = Km[i][jj];
  }
}

// ---------------- RMSNorm (f32 in -> bf16 out) ----------------
__global__ __launch_bounds__(256) void rmsnorm_k(const float* __restrict__ in,
                                                 const float* __restrict__ w,
                                                 bf16* __restrict__ out) {
  int row = blockIdx.x;
  const float* r = in + (size_t)row * DDIM;
  int tid = threadIdx.x;
  float ss = 0.0f;
  for (int i = tid; i < DDIM; i += 256) {
    float v = r[i];
    ss += v * v;
  }
  for (int off = 32; off > 0; off >>= 1) ss += __shfl_down(ss, off);
  __shared__ float red[4];
  if ((tid & 63) == 0) red[tid >> 6] = ss;
  __syncthreads();
  float tot = red[0] + red[1] + red[2] + red[3];
  float sc = rsqrtf(tot / (float)DDIM + EPSV);
  bf16* o = out + (size_t)row * DDIM;
  for (int i = tid; i < DDIM; i += 256) o[i] = f2b(r[i] * sc * w[i]);
}

// ------- MFMA GEMM, m97 structure: 128x128 tile, BK=32, global_load_lds -----
// ODT: 0=f32 out, 1=bf16 out.  EPI: 0=none, 1=gelu(exact erf), 2=add residual
template <int ODT, int EPI>
__global__ __launch_bounds__(256) void gemm_lds(const bf16* __restrict__ A,
                                                const bf16* __restrict__ W,
                                                const float* __restrict__ bias,
                                                const float* __restrict__ res,
                                                void* __restrict__ outp,
                                                int M, int N, int K) {
  __shared__ bf16 As[128 * 32];
  __shared__ bf16 Bs[128 * 32];
  int tid = threadIdx.x;
  int lane = tid & 63, wv = tid >> 6;
  int ml = lane & 15, quad = lane >> 4;
  int wr = wv >> 1, wc = wv & 1;
  int m0 = blockIdx.x * 128, n0 = blockIdx.y * 128;
  f4 acc[4][4] = {};
  for (int k0 = 0; k0 < K; k0 += 32) {
#pragma unroll
    for (int it = 0; it < 2; it++) {
      int c = it * 256 + tid;             // 512 16B-chunks per tile
      int row = c >> 2, kc = (c & 3) * 8;
      glds16(&As[c * 8], A + (size_t)(m0 + row) * K + k0 + kc);
      glds16(&Bs[c * 8], W + (size_t)(n0 + row) * K + k0 + kc);
    }
    __syncthreads();
    bf8 af[4], bfr[4];
#pragma unroll
    for (int mi = 0; mi < 4; mi++)
      af[mi] = ld8(&As[(wr * 64 + mi * 16 + ml) * 32 + quad * 8]);
#pragma unroll
    for (int ni = 0; ni < 4; ni++)
      bfr[ni] = ld8(&Bs[(wc * 64 + ni * 16 + ml) * 32 + quad * 8]);
#pragma unroll
    for (int mi = 0; mi < 4; mi++)
#pragma unroll
      for (int ni = 0; ni < 4; ni++)
        acc[mi][ni] = MFMA(af[mi], bfr[ni], acc[mi][ni]);
    __syncthreads();
  }
#pragma unroll
  for (int mi = 0; mi < 4; mi++)
#pragma unroll
    for (int ni = 0; ni < 4; ni++)
#pragma unroll
      for (int r = 0; r < 4; r++) {
        int row = m0 + wr * 64 + mi * 16 + quad * 4 + r;
        int col = n0 + wc * 64 + ni * 16 + ml;
        size_t idx = (size_t)row * N + col;
        float v = acc[mi][ni][r] + bias[col];
        if (EPI == 1) v = 0.5f * v * (1.0f + erff(v * 0.70710678118654752f));
        if (EPI == 2) v += res[idx];
        if (ODT == 1) ((bf16*)outp)[idx] = f2b(v);
        else ((float*)outp)[idx] = v;
      }
}

// ------- MFMA GEMM half-K partial: 128x128 tile over K-slice, f32 out -------
// A/W pointers pre-offset to the K-slice start; KS = slice length; LDK = full
// row stride. Writes raw f32 partial (no bias/epilogue).
__global__ __launch_bounds__(256) void gemm_part(const bf16* __restrict__ A,
                                                 const bf16* __restrict__ W,
                                                 float* __restrict__ P,
                                                 int M, int N, int KS, int LDK) {
  __shared__ bf16 As[128 * 32];
  __shared__ bf16 Bs[128 * 32];
  int tid = threadIdx.x;
  int lane = tid & 63, wv = tid >> 6;
  int ml = lane & 15, quad = lane >> 4;
  int wr = wv >> 1, wc = wv & 1;
  int m0 = blockIdx.x * 128, n0 = blockIdx.y * 128;
  f4 acc[4][4] = {};
  for (int k0 = 0; k0 < KS; k0 += 32) {
#pragma unroll
    for (int it = 0; it < 2; it++) {
      int c = it * 256 + tid;
      int row = c >> 2, kc = (c & 3) * 8;
      glds16(&As[c * 8], A + (size_t)(m0 + row) * LDK + k0 + kc);
      glds16(&Bs[c * 8], W + (size_t)(n0 + row) * LDK + k0 + kc);
    }
    __syncthreads();
    bf8 af[4], bfr[4];
#pragma unroll
    for (int mi = 0; mi < 4; mi++)
      af[mi] = ld8(&As[(wr * 64 + mi * 16 + ml) * 32 + quad * 8]);
#pragma unroll
    for (int ni = 0; ni < 4; ni++)
      bfr[ni] = ld8(&Bs[(wc * 64 + ni * 16 + ml) * 32 + quad * 8]);
#pragma unroll
    for (int mi = 0; mi < 4; mi++)
#pragma unroll
      for (int ni = 0; ni < 4; ni++)
        acc[mi][ni] = MFMA(af[mi], bfr[ni], acc[mi][ni]);
    __syncthreads();
  }
#pragma unroll
  for (int mi = 0; mi < 4; mi++)
#pragma unroll
    for (int ni = 0; ni < 4; ni++)
#pragma unroll
      for (int r = 0; r < 4; r++) {
        int row = m0 + wr * 64 + mi * 16 + quad * 4 + r;
        int col = n0 + wc * 64 + ni * 16 + ml;
        P[(size_t)row * N + col] = acc[mi][ni][r];
      }
}

// ---- ffn2 finish: AO += P0 + P1 + bias (vectorized, one row per block) ----
__global__ __launch_bounds__(256) void ffn2_fin(const float* __restrict__ P0,
                                                const float* __restrict__ P1,
                                                const float* __restrict__ bias,
                                                float* __restrict__ AO) {
  int row = blockIdx.x;
  int i = threadIdx.x * 4;
  const float* p0 = P0 + (size_t)row * DDIM;
  const float* p1 = P1 + (size_t)row * DDIM;
  float* ao = AO + (size_t)row * DDIM;
  float4 a = *(const float4*)(p0 + i);
  float4 b = *(const float4*)(p1 + i);
  float4 c = *(const float4*)(bias + i);
  float4 d = *(const float4*)(ao + i);
  float4 o;
  o.x = a.x + b.x + c.x + d.x;
  o.y = a.y + b.y + c.y + d.y;
  o.z = a.z + b.z + c.z + d.z;
  o.w = a.w + b.w + c.w + d.w;
  *(float4*)(ao + i) = o;
}

// ------- MFMA GEMM, BM=64 x BN=128 variant (2 blocks/CU for N=1024 GEMMs) ---
template <int ODT, int EPI>
__global__ __launch_bounds__(256) void gemm_lds64(const bf16* __restrict__ A,
                                                  const bf16* __restrict__ W,
                                                  const float* __restrict__ bias,
                                                  const float* __restrict__ res,
                                                  void* __restrict__ outp,
                                                  int M, int N, int K) {
  __shared__ bf16 As[64 * 32];
  __shared__ bf16 Bs[128 * 32];
  int tid = threadIdx.x;
  int lane = tid & 63, wv = tid >> 6;
  int ml = lane & 15, quad = lane >> 4;
  int wr = wv & 1, wc = wv >> 1;        // wave tile: 32 rows x 64 cols
  int m0 = blockIdx.x * 64, n0 = blockIdx.y * 128;
  f4 acc[2][4] = {};
  for (int k0 = 0; k0 < K; k0 += 32) {
    {
      int c = tid;                      // A: 256 chunks
      int row = c >> 2, kc = (c & 3) * 8;
      glds16(&As[c * 8], A + (size_t)(m0 + row) * K + k0 + kc);
    }
#pragma unroll
    for (int it = 0; it < 2; it++) {    // B: 512 chunks
      int c = it * 256 + tid;
      int row = c >> 2, kc = (c & 3) * 8;
      glds16(&Bs[c * 8], W + (size_t)(n0 + row) * K + k0 + kc);
    }
    __syncthreads();
    bf8 af[2], bfr[4];
#pragma unroll
    for (int mi = 0; mi < 2; mi++)
      af[mi] = ld8(&As[(wr * 32 + mi * 16 + ml) * 32 + quad * 8]);
#pragma unroll
    for (int ni = 0; ni < 4; ni++)
      bfr[ni] = ld8(&Bs[(wc * 64 + ni * 16 + ml) * 32 + quad * 8]);
#pragma unroll
    for (int mi = 0; mi < 2; mi++)
#pragma unroll
      for (int ni = 0; ni < 4; ni++)
        acc[mi][ni] = MFMA(af[mi], bfr[ni], acc[mi][ni]);
    __syncthreads();
  }
#pragma unroll
  for (int mi = 0; mi < 2; mi++)
#pragma unroll
    for (int ni = 0; ni < 4; ni++)
#pragma unroll
      for (int r = 0; r < 4; r++) {
        int row = m0 + wr * 32 + mi * 16 + quad * 4 + r;
        int col = n0 + wc * 64 + ni * 16 + ml;
        size_t idx = (size_t)row * N + col;
        float v = acc[mi][ni][r] + bias[col];
        if (EPI == 1) v = 0.5f * v * (1.0f + erff(v * 0.70710678118654752f));
        if (EPI == 2) v += res[idx];
        if (ODT == 1) ((bf16*)outp)[idx] = f2b(v);
        else ((float*)outp)[idx] = v;
      }
}

// ---------------- V transpose: VT[b,h,d,s] = qkv[b,s,2D + h*64 + d] --------
__global__ __launch_bounds__(256) void vtrans(const bf16* __restrict__ qkv,
                                              bf16* __restrict__ VT) {
  int bid = blockIdx.x;
  int st = bid % (SS / 64);
  int h = (bid / (SS / 64)) % NHEAD;
  int b = bid / ((SS / 64) * NHEAD);
  __shared__ bf16 tile[64][65];
  int s0 = st * 64;
  int tid = threadIdx.x;
  for (int it = 0; it < 16; it++) {
    int sl = it * 4 + (tid >> 6), dl = tid & 63;
    tile[sl][dl] = qkv[(size_t)(b * SS + s0 + sl) * (3 * DDIM) + 2 * DDIM + h * 64 + dl];
  }
  __syncthreads();
  for (int it = 0; it < 16; it++) {
    int dl = it * 4 + (tid >> 6), sl = tid & 63;
    VT[((size_t)(b * NHEAD + h) * 64 + dl) * SS + s0 + sl] = tile[sl][dl];
  }
}

// ---- Flash attention (R7 structure, best measured 126us): antithetic pairing
// + K/V register double-buffer; 512 uniform blocks; writes OB directly. ----
__device__ __forceinline__ void loadK(bf8* dst, const bf16* kbase, int k0,
                                      int ml, int quad) {
#pragma unroll
  for (int kk = 0; kk < 2; kk++)
#pragma unroll
    for (int c = 0; c < 4; c++)
      dst[kk * 4 + c] =
          ld8(kbase + (size_t)(k0 + c * 16 + ml) * (3 * DDIM) + kk * 32 + quad * 8);
}
__device__ __forceinline__ void loadV(bf8* dst, const bf16* vbase, int k0,
                                      int ml, int quad) {
#pragma unroll
  for (int c = 0; c < 4; c++)
#pragma unroll
    for (int kk = 0; kk < 2; kk++)
      dst[c * 2 + kk] =
          ld8(vbase + (size_t)(c * 16 + ml) * SS + k0 + kk * 32 + quad * 8);
}

__device__ __forceinline__ void attend16(const bf16* __restrict__ qkv,
                                         const bf16* __restrict__ kbase,
                                         const bf16* __restrict__ vbase,
                                         bf16* __restrict__ obuf,
                                         int b, int h, int q0,
                                         int ml, int quad, bf16 (*pl)[64]) {
  const float SC = 0.125f * 1.44269504089f;   // 1/sqrt(64) * log2(e)
  bf8 qf[2];
#pragma unroll
  for (int kk = 0; kk < 2; kk++)
    qf[kk] = ld8(qkv + (size_t)(b * SS + q0 + ml) * (3 * DDIM) + h * 64 + kk * 32 + quad * 8);

  f4 oacc[4] = {{0,0,0,0},{0,0,0,0},{0,0,0,0},{0,0,0,0}};
  float m_r[4], l_r[4];
#pragma unroll
  for (int r = 0; r < 4; r++) { m_r[r] = -1e30f; l_r[r] = 0.0f; }

  int nkt = (q0 >> 6) + 1;
  bf8 kc[8], vc[8], kn[8], vn[8];
  loadK(kc, kbase, 0, ml, quad);
  loadV(vc, vbase, 0, ml, quad);
  for (int kt = 0; kt < nkt; kt++) {
    int ktn = (kt + 1 < nkt) ? kt + 1 : kt;   // clamped prefetch (straight-line)
    loadK(kn, kbase, ktn * 64, ml, quad);
    loadV(vn, vbase, ktn * 64, ml, quad);
    int k0 = kt * 64;
    f4 sacc[4] = {{0,0,0,0},{0,0,0,0},{0,0,0,0},{0,0,0,0}};
#pragma unroll
    for (int kk = 0; kk < 2; kk++)
#pragma unroll
      for (int c = 0; c < 4; c++)
        sacc[c] = MFMA(qf[kk], kc[kk * 4 + c], sacc[c]);
    float sv[4][4];
#pragma unroll
    for (int c = 0; c < 4; c++)
#pragma unroll
      for (int r = 0; r < 4; r++) sv[c][r] = sacc[c][r] * SC;
    if (kt == nkt - 1) {                 // only the diagonal tile needs masking
#pragma unroll
      for (int c = 0; c < 4; c++)
#pragma unroll
        for (int r = 0; r < 4; r++) {
          int qi = q0 + quad * 4 + r;
          int kj = k0 + c * 16 + ml;
          if (kj > qi) sv[c][r] = -1e9f;
        }
    }
    float alpha[4];
#pragma unroll
    for (int r = 0; r < 4; r++) {
      float mx = fmaxf(fmaxf(sv[0][r], sv[1][r]), fmaxf(sv[2][r], sv[3][r]));
#pragma unroll
      for (int off = 1; off < 16; off <<= 1) mx = fmaxf(mx, __shfl_xor(mx, off));
      float mn = fmaxf(m_r[r], mx);
      float rs = 0.0f;
#pragma unroll
      for (int c = 0; c < 4; c++) {
        float p = fexp2(sv[c][r] - mn);
        sv[c][r] = p;
        rs += p;
      }
#pragma unroll
      for (int off = 1; off < 16; off <<= 1) rs += __shfl_xor(rs, off);
      alpha[r] = fexp2(m_r[r] - mn);
      l_r[r] = l_r[r] * alpha[r] + rs;
      m_r[r] = mn;
    }
#pragma unroll
    for (int c = 0; c < 4; c++)
#pragma unroll
      for (int r = 0; r < 4; r++) oacc[c][r] *= alpha[r];
    // C-layout -> A-layout transform via per-wave LDS (no barriers: private)
#pragma unroll
    for (int c = 0; c < 4; c++)
#pragma unroll
      for (int r = 0; r < 4; r++)
        pl[quad * 4 + r][c * 16 + ml] = f2b(sv[c][r]);
    bf8 pf[2];
#pragma unroll
    for (int kk = 0; kk < 2; kk++) pf[kk] = ld8(&pl[ml][kk * 32 + quad * 8]);
#pragma unroll
    for (int c = 0; c < 4; c++)
#pragma unroll
      for (int kk = 0; kk < 2; kk++)
        oacc[c] = MFMA(pf[kk], vc[c * 2 + kk], oacc[c]);
#pragma unroll
    for (int i = 0; i < 8; i++) { kc[i] = kn[i]; vc[i] = vn[i]; }
  }
#pragma unroll
  for (int c = 0; c < 4; c++)
#pragma unroll
    for (int r = 0; r < 4; r++) {
      int row = q0 + quad * 4 + r;
      obuf[(size_t)(b * SS + row) * DDIM + h * 64 + c * 16 + ml] =
          f2b(oacc[c][r] / l_r[r]);
    }
}

__global__ __launch_bounds__(256, 2) void flash_attn(const bf16* __restrict__ qkv,
                                                     const bf16* __restrict__ VT,
                                                     bf16* __restrict__ obuf) {
  int bid = blockIdx.x;                 // grid: BB*NHEAD*16 = 512 uniform blocks
  int blk = bid & 15;
  int h = (bid >> 4) & 15;
  int b = bid >> 8;
  int wv = threadIdx.x >> 6, lane = threadIdx.x & 63;
  int ml = lane & 15, quad = lane >> 4;
  int idx = blk * 4 + wv;               // 0..63

  __shared__ __align__(16) bf16 plds[4][16][64];
  bf16 (*pl)[64] = plds[wv];            // per-wave private slice

  const bf16* kbase = qkv + (size_t)b * SS * (3 * DDIM) + DDIM + h * 64;
  const bf16* vbase = VT + (size_t)(b * NHEAD + h) * 64 * SS;

  attend16(qkv, kbase, vbase, obuf, b, h, idx * 16, ml, quad, pl);
  attend16(qkv, kbase, vbase, obuf, b, h, (127 - idx) * 16, ml, quad, pl);
}

// ---------------- final: out = (y+ffn) + mhc ----------------
__global__ __launch_bounds__(256) void final_k(const float* __restrict__ yffn,
                                               const float* __restrict__ xd,
                                               const float* __restrict__ hres,
                                               const float* __restrict__ gres,
                                               float* __restrict__ out) {
  int row = blockIdx.x;  // [B*S]
  int b = row / SS;
  int tid = threadIdx.x;
  __shared__ float cf[8][8];
  if (tid < 64) cf[tid >> 3][tid & 7] = hres[tid] * gres[b * NSTR + (tid & 7)];
  __syncthreads();
  const float* yr = yffn + (size_t)row * DDIM;
  const float* xr = xd + (size_t)row * DDIM;
  float* o = out + (size_t)row * DDIM;
  for (int i = tid; i < DDIM; i += 256) {
    int m = i >> 7, dd = i & 127;
    float acc = yr[i];
#pragma unroll
    for (int n = 0; n < 8; n++) acc += cf[m][n] * xr[n * SDIMC + dd];
    o[i] = acc;
  }
}

extern "C" void kernel_launch(void* const* d_in, const int* in_sizes, int n_in,
                              void* d_out, int out_size, void* d_ws, size_t ws_size,
                              hipStream_t stream) {
  const float* x     = (const float*)d_in[0];
  const float* decay = (const float*)d_in[3];
  const float* gw    = (const float*)d_in[4];
  const float* gb    = (const float*)d_in[5];
  const float* phi   = (const float*)d_in[6];
  const float* ln1   = (const float*)d_in[7];
  const float* ln2   = (const float*)d_in[8];
  const float* w1    = (const float*)d_in[9];
  const float* b1    = (const float*)d_in[10];
  const float* w2    = (const float*)d_in[11];
  const float* b2    = (const float*)d_in[12];
  const float* ipw   = (const float*)d_in[13];
  const float* ipb   = (const float*)d_in[14];
  const float* ow    = (const float*)d_in[15];
  const float* obs   = (const float*)d_in[16];
  float* out = (float*)d_out;

  // ---- workspace layout (105 MB total) ----
  const size_t MB = 1048576ull;
  char* wsp = (char*)d_ws;
  float* SA   = (float*)(wsp);                 // 128 KB  chunk states / sums
  float* SIN  = (float*)(wsp + 131072ull);     // 128 KB  incoming states
  float* GRES = (float*)(wsp + 262144ull);     // 64 B
  float* HRES = (float*)(wsp + 262208ull);     // 256 B
  float* XD   = (float*)(wsp + 1 * MB);        // 16 MB   x_delta (f32), live to end
  float* AO   = (float*)(wsp + 17 * MB);       // 16 MB   y; then y+ffn in-place
  bf16*  NORM = (bf16*)(wsp + 33 * MB);        // 8 MB    normed/normed2 (dead after ffn1)
  bf16*  OB   = (bf16*)(wsp + 41 * MB);        // 8 MB    attn out (dead after outproj)
  bf16*  QKV  = (bf16*)(wsp + 49 * MB);        // 24 MB   (dead after flash)
  bf16*  VT   = (bf16*)(wsp + 73 * MB);        // 8 MB    (dead after flash)
  bf16*  HB   = (bf16*)(wsp + 49 * MB);        // 32 MB   gelu hidden, ALIASES QKV+VT
  bf16*  WIPW = (bf16*)(wsp + 81 * MB);        // 6 MB    in_proj_w bf16 (dead after qkv)
  bf16*  WOW  = (bf16*)(wsp + 87 * MB);        // 2 MB    out_w bf16 (dead after outproj)
  bf16*  W1B  = (bf16*)(wsp + 89 * MB);        // 8 MB    w1 bf16 (dead after ffn1)
  bf16*  W2B  = (bf16*)(wsp + 97 * MB);        // 8 MB    w2 bf16 (live thru ffn2)
  // ffn2 split-K partials (f32, 16 MB each), live only during ffn2:
  // PK0 over NORM+OB (33-49 MB, both dead), PK1 over WIPW/WOW/W1B (81-97, dead)
  float* PK0  = (float*)(wsp + 33 * MB);
  float* PK1  = (float*)(wsp + 81 * MB);

  // 0: convert all GEMM weights f32 -> bf16 (single launch, float4)
  cvt_all<<<dim3(12 * DDIM * DDIM / 1024), dim3(256), 0, stream>>>(
      ipw, ow, w1, w2, WIPW, WOW, W1B, W2B);

  // 1-3: delta operator scan
  delta_passA<<<dim3(BB * NCH * DDIM / 256), dim3(256), 0, stream>>>(x, decay, SA);
  delta_passB<<<dim3(BB * DDIM / 256), dim3(256), 0, stream>>>(SA, decay, SIN);
  delta_passC<<<dim3(BB * NCH * DDIM / 256), dim3(256), 0, stream>>>(x, decay, SIN, XD, SA);
  // 4: gates + sinkhorn
  gates_sinkhorn<<<dim3(1), dim3(1024), 0, stream>>>(SA, gw, gb, phi, GRES, HRES);
  // 5: rmsnorm1 (XD -> NORM)
  rmsnorm_k<<<dim3(BB * SS), dim3(256), 0, stream>>>(XD, ln1, NORM);
  // 6: qkv = NORM @ in_proj_w.T + in_proj_b   [4096 x 3072]
  gemm_lds<1, 0><<<dim3(32, 24), dim3(256), 0, stream>>>(NORM, WIPW, ipb, nullptr,
                                                         QKV, BB * SS, 3 * DDIM, DDIM);
  // 7: V transpose
  vtrans<<<dim3(BB * NHEAD * (SS / 64)), dim3(256), 0, stream>>>(QKV, VT);
  // 8: flash attention -> OB (R7 best-known structure)
  flash_attn<<<dim3(BB * NHEAD * 16), dim3(256), 0, stream>>>(QKV, VT, OB);
  // 9: out-proj + residual(XD) -> AO (= y)
  gemm_lds64<0, 2><<<dim3(64, 8), dim3(256), 0, stream>>>(OB, WOW, obs, XD,
                                                          AO, BB * SS, DDIM, DDIM);
  // 10: rmsnorm2 (AO -> NORM)
  rmsnorm_k<<<dim3(BB * SS), dim3(256), 0, stream>>>(AO, ln2, NORM);
  // 11: ffn1 + gelu -> HB   [4096 x 4096]  (HB aliases dead QKV/VT)
  gemm_lds<1, 1><<<dim3(32, 32), dim3(256), 0, stream>>>(NORM, W1B, b1, nullptr,
                                                         HB, BB * SS, 4 * DDIM, DDIM);
  // 12: ffn2 split-K=2 with full 128x128 tiles (2x512 blocks, 64 K-iters each)
  gemm_part<<<dim3(32, 8), dim3(256), 0, stream>>>(HB, W2B, PK0,
                                                   BB * SS, DDIM, 2 * DDIM, 4 * DDIM);
  gemm_part<<<dim3(32, 8), dim3(256), 0, stream>>>(HB + 2 * DDIM, W2B + 2 * DDIM, PK1,
                                                   BB * SS, DDIM, 2 * DDIM, 4 * DDIM);
  // 12b: AO += PK0 + PK1 + b2   (y + ffn_out, in-place)
  ffn2_fin<<<dim3(BB * SS), dim3(256), 0, stream>>>(PK0, PK1, b2, AO);
  // 13: final out = AO + mhc(XD)
  final_k<<<dim3(BB * SS), dim3(256), 0, stream>>>(AO, XD, HRES, GRES, out);
}

// Round 11
// 469.200 us; speedup vs baseline: 1.2157x; 1.2157x over previous
//
#include <hip/hip_runtime.h>
#include <hip/hip_bf16.h>
#include <math.h>

// Problem constants
#define BB 2
#define SS 2048
#define DDIM 1024
#define NHEAD 16
#define NSTR 8
#define SDIMC 128
#define NCH 16      // chunks for delta scan
#define CLEN 128    // chunk length
#define EPSV 1e-6f

using bf16 = __hip_bfloat16;
typedef __attribute__((ext_vector_type(8))) __bf16 bf8;
typedef __attribute__((ext_vector_type(4))) float f4;

__device__ __forceinline__ bf16 f2b(float v) { return __float2bfloat16(v); }
__device__ __forceinline__ bf8 ld8(const bf16* p) { return *(const bf8*)p; }
__device__ __forceinline__ f4 MFMA(bf8 a, bf8 b, f4 c) {
  return __builtin_amdgcn_mfma_f32_16x16x32_bf16(a, b, c, 0, 0, 0);
}
__device__ __forceinline__ float sigm(float x) { return 1.0f / (1.0f + expf(-x)); }
__device__ __forceinline__ float fexp2(float x) { return __builtin_amdgcn_exp2f(x); }

// async global->LDS 16B copy (m97 pattern; LDS dest must be uniform + lane*16)
__device__ __forceinline__ void glds16(bf16* l, const bf16* g) {
  __builtin_amdgcn_global_load_lds(
      (const __attribute__((address_space(1))) unsigned int*)g,
      (__attribute__((address_space(3))) unsigned int*)l, 16, 0, 0);
}

// ---------------- f32 -> bf16 weight conversion (all 4 weights, one launch) --
__global__ __launch_bounds__(256) void cvt_all(const float* __restrict__ ipw,
                                               const float* __restrict__ ow,
                                               const float* __restrict__ w1,
                                               const float* __restrict__ w2,
                                               bf16* __restrict__ WIPW,
                                               bf16* __restrict__ WOW,
                                               bf16* __restrict__ W1B,
                                               bf16* __restrict__ W2B) {
  const int S1 = 3 * DDIM * DDIM, S2 = S1 + DDIM * DDIM,
            S3 = S2 + 4 * DDIM * DDIM;
  int i4 = (blockIdx.x * 256 + threadIdx.x) * 4;   // grid covers 12.58M elems
  const float* src;
  bf16* dst;
  int off;
  if (i4 < S1)      { src = ipw; dst = WIPW; off = i4; }
  else if (i4 < S2) { src = ow;  dst = WOW;  off = i4 - S1; }
  else if (i4 < S3) { src = w1;  dst = W1B;  off = i4 - S2; }
  else              { src = w2;  dst = W2B;  off = i4 - S3; }
  float4 v = *(const float4*)(src + off);
  dst[off]     = f2b(v.x);
  dst[off + 1] = f2b(v.y);
  dst[off + 2] = f2b(v.z);
  dst[off + 3] = f2b(v.w);
}

// ---------------- Delta operator: 3-pass chunked affine scan ----------------
__global__ __launch_bounds__(256) void delta_passA(const float* __restrict__ x,
                                                   const float* __restrict__ decay,
                                                   float* __restrict__ SA) {
  int idx = blockIdx.x * 256 + threadIdx.x;      // [b][c][d]
  int d = idx % DDIM;
  int c = (idx / DDIM) % NCH;
  int b = idx / (DDIM * NCH);
  float beta = sigm(decay[d]);
  float omb = 1.0f - beta;
  const float* xp = x + ((size_t)(b * SS + c * CLEN)) * DDIM + d;
  float s = 0.0f;
  for (int j = 0; j < CLEN; j++) {
    float xv = xp[(size_t)j * DDIM];
    s = beta * s + omb * xv;
  }
  SA[idx] = s;
}

__global__ __launch_bounds__(256) void delta_passB(const float* __restrict__ SA,
                                                   const float* __restrict__ decay,
                                                   float* __restrict__ SIN) {
  int idx = blockIdx.x * 256 + threadIdx.x;      // [b][d]
  int d = idx % DDIM;
  int b = idx / DDIM;
  float beta = sigm(decay[d]);
  float p = beta;
  for (int i = 0; i < 7; i++) p *= p;            // beta^128
  float s = 0.0f;
  for (int c = 0; c < NCH; c++) {
    SIN[(b * NCH + c) * DDIM + d] = s;
    s = p * s + SA[(b * NCH + c) * DDIM + d];
  }
}

__global__ __launch_bounds__(256) void delta_passC(const float* __restrict__ x,
                                                   const float* __restrict__ decay,
                                                   const float* __restrict__ SIN,
                                                   float* __restrict__ XD,
                                                   float* __restrict__ SA) {
  int idx = blockIdx.x * 256 + threadIdx.x;      // [b][c][d]
  int d = idx % DDIM;
  int c = (idx / DDIM) % NCH;
  int b = idx / (DDIM * NCH);
  float beta = sigm(decay[d]);
  float omb = 1.0f - beta;
  const float* xp = x + ((size_t)(b * SS + c * CLEN)) * DDIM + d;
  float* xdp = XD + ((size_t)(b * SS + c * CLEN)) * DDIM + d;
  float s = SIN[idx];
  float sum = 0.0f;
  for (int j = 0; j < CLEN; j++) {
    float xv = xp[(size_t)j * DDIM];
    float o = xv - s;
    xdp[(size_t)j * DDIM] = o;
    sum += o;
    s = beta * s + omb * xv;
  }
  SA[idx] = sum;
}

// ---------------- gates (g_res) + sinkhorn ----------------
__global__ __launch_bounds__(1024) void gates_sinkhorn(const float* __restrict__ SA,
                                                       const float* __restrict__ gw,
                                                       const float* __restrict__ gb,
                                                       const float* __restrict__ phi,
                                                       float* __restrict__ gres,
                                                       float* __restrict__ hres) {
  int tid = threadIdx.x;
  int wave = tid >> 6, lane = tid & 63;
  int b = wave >> 3, j = wave & 7;               // 16 waves: (b, gate j)
  float acc = 0.0f;
  for (int d = lane; d < DDIM; d += 64) {
    float xs = 0.0f;
    for (int c = 0; c < NCH; c++) xs += SA[(b * NCH + c) * DDIM + d];
    xs *= (1.0f / (float)SS);
    acc += xs * gw[(2 * NSTR + j) * DDIM + d];
  }
  for (int off = 32; off > 0; off >>= 1) acc += __shfl_down(acc, off);
  if (lane == 0) gres[b * NSTR + j] = sigm(acc + gb[2 * NSTR + j]);
  __syncthreads();
  if (tid == 0) {
    float Km[8][8];
    for (int i = 0; i < 8; i++)
      for (int jj = 0; jj < 8; jj++) Km[i][jj] = expf(phi[i * 8 + jj]);
    for (int it = 0; it < 15; it++) {
      for (int i = 0; i < 8; i++) {
        float rs = 0.0f;
        for (int jj = 0; jj < 8; jj++) rs += Km[i][jj];
        float inv = 1.0f / rs;
        for (int jj = 0; jj < 8; jj++) Km[i][jj] *= inv;
      }
      for (int jj = 0; jj < 8; jj++) {
        float cs = 0.0f;
        for (int i = 0; i < 8; i++) cs += Km[i][jj];
        float inv = 1.0f / cs;
        for (int i = 0; i < 8; i++) Km[i][jj] *= inv;
      }
    }
    for (int i = 0; i < 8; i++)
      for (int jj = 0; jj < 8; jj++) hres[i * 8 + jj] = Km[i][jj];
  }
}

// ---------------- RMSNorm (f32 in -> bf16 out) ----------------
__global__ __launch_bounds__(256) void rmsnorm_k(const float* __restrict__ in,
                                                 const float* __restrict__ w,
                                                 bf16* __restrict__ out) {
  int row = blockIdx.x;
  const float* r = in + (size_t)row * DDIM;
  int tid = threadIdx.x;
  float ss = 0.0f;
  for (int i = tid; i < DDIM; i += 256) {
    float v = r[i];
    ss += v * v;
  }
  for (int off = 32; off > 0; off >>= 1) ss += __shfl_down(ss, off);
  __shared__ float red[4];
  if ((tid & 63) == 0) red[tid >> 6] = ss;
  __syncthreads();
  float tot = red[0] + red[1] + red[2] + red[3];
  float sc = rsqrtf(tot / (float)DDIM + EPSV);
  bf16* o = out + (size_t)row * DDIM;
  for (int i = tid; i < DDIM; i += 256) o[i] = f2b(r[i] * sc * w[i]);
}

// ------- MFMA GEMM, m97 structure: 128x128 tile, BK=32, global_load_lds -----
// ODT: 0=f32 out, 1=bf16 out.  EPI: 0=none, 1=gelu(exact erf), 2=add residual
template <int ODT, int EPI>
__global__ __launch_bounds__(256) void gemm_lds(const bf16* __restrict__ A,
                                                const bf16* __restrict__ W,
                                                const float* __restrict__ bias,
                                                const float* __restrict__ res,
                                                void* __restrict__ outp,
                                                int M, int N, int K) {
  __shared__ bf16 As[128 * 32];
  __shared__ bf16 Bs[128 * 32];
  int tid = threadIdx.x;
  int lane = tid & 63, wv = tid >> 6;
  int ml = lane & 15, quad = lane >> 4;
  int wr = wv >> 1, wc = wv & 1;
  int m0 = blockIdx.x * 128, n0 = blockIdx.y * 128;
  f4 acc[4][4] = {};
  for (int k0 = 0; k0 < K; k0 += 32) {
#pragma unroll
    for (int it = 0; it < 2; it++) {
      int c = it * 256 + tid;             // 512 16B-chunks per tile
      int row = c >> 2, kc = (c & 3) * 8;
      glds16(&As[c * 8], A + (size_t)(m0 + row) * K + k0 + kc);
      glds16(&Bs[c * 8], W + (size_t)(n0 + row) * K + k0 + kc);
    }
    __syncthreads();
    bf8 af[4], bfr[4];
#pragma unroll
    for (int mi = 0; mi < 4; mi++)
      af[mi] = ld8(&As[(wr * 64 + mi * 16 + ml) * 32 + quad * 8]);
#pragma unroll
    for (int ni = 0; ni < 4; ni++)
      bfr[ni] = ld8(&Bs[(wc * 64 + ni * 16 + ml) * 32 + quad * 8]);
#pragma unroll
    for (int mi = 0; mi < 4; mi++)
#pragma unroll
      for (int ni = 0; ni < 4; ni++)
        acc[mi][ni] = MFMA(af[mi], bfr[ni], acc[mi][ni]);
    __syncthreads();
  }
#pragma unroll
  for (int mi = 0; mi < 4; mi++)
#pragma unroll
    for (int ni = 0; ni < 4; ni++)
#pragma unroll
      for (int r = 0; r < 4; r++) {
        int row = m0 + wr * 64 + mi * 16 + quad * 4 + r;
        int col = n0 + wc * 64 + ni * 16 + ml;
        size_t idx = (size_t)row * N + col;
        float v = acc[mi][ni][r] + bias[col];
        if (EPI == 1) v = 0.5f * v * (1.0f + erff(v * 0.70710678118654752f));
        if (EPI == 2) v += res[idx];
        if (ODT == 1) ((bf16*)outp)[idx] = f2b(v);
        else ((float*)outp)[idx] = v;
      }
}

// ------- ffn2 split-K=2, ONE launch, grid (32,8,2): z picks K-slice+buffer ---
__global__ __launch_bounds__(256) void gemm_part2(const bf16* __restrict__ A,
                                                  const bf16* __restrict__ W,
                                                  float* __restrict__ P0,
                                                  float* __restrict__ P1,
                                                  int M, int N, int KS, int LDK) {
  __shared__ bf16 As[128 * 32];
  __shared__ bf16 Bs[128 * 32];
  int tid = threadIdx.x;
  int lane = tid & 63, wv = tid >> 6;
  int ml = lane & 15, quad = lane >> 4;
  int wr = wv >> 1, wc = wv & 1;
  int m0 = blockIdx.x * 128, n0 = blockIdx.y * 128;
  const bf16* Ab = A + blockIdx.z * KS;
  const bf16* Wb = W + blockIdx.z * KS;
  float* P = blockIdx.z ? P1 : P0;
  f4 acc[4][4] = {};
  for (int k0 = 0; k0 < KS; k0 += 32) {
#pragma unroll
    for (int it = 0; it < 2; it++) {
      int c = it * 256 + tid;
      int row = c >> 2, kc = (c & 3) * 8;
      glds16(&As[c * 8], Ab + (size_t)(m0 + row) * LDK + k0 + kc);
      glds16(&Bs[c * 8], Wb + (size_t)(n0 + row) * LDK + k0 + kc);
    }
    __syncthreads();
    bf8 af[4], bfr[4];
#pragma unroll
    for (int mi = 0; mi < 4; mi++)
      af[mi] = ld8(&As[(wr * 64 + mi * 16 + ml) * 32 + quad * 8]);
#pragma unroll
    for (int ni = 0; ni < 4; ni++)
      bfr[ni] = ld8(&Bs[(wc * 64 + ni * 16 + ml) * 32 + quad * 8]);
#pragma unroll
    for (int mi = 0; mi < 4; mi++)
#pragma unroll
      for (int ni = 0; ni < 4; ni++)
        acc[mi][ni] = MFMA(af[mi], bfr[ni], acc[mi][ni]);
    __syncthreads();
  }
#pragma unroll
  for (int mi = 0; mi < 4; mi++)
#pragma unroll
    for (int ni = 0; ni < 4; ni++)
#pragma unroll
      for (int r = 0; r < 4; r++) {
        int row = m0 + wr * 64 + mi * 16 + quad * 4 + r;
        int col = n0 + wc * 64 + ni * 16 + ml;
        P[(size_t)row * N + col] = acc[mi][ni][r];
      }
}

// ------- MFMA GEMM, BM=64 x BN=128 variant (2 blocks/CU for N=1024 GEMMs) ---
template <int ODT, int EPI>
__global__ __launch_bounds__(256) void gemm_lds64(const bf16* __restrict__ A,
                                                  const bf16* __restrict__ W,
                                                  const float* __restrict__ bias,
                                                  const float* __restrict__ res,
                                                  void* __restrict__ outp,
                                                  int M, int N, int K) {
  __shared__ bf16 As[64 * 32];
  __shared__ bf16 Bs[128 * 32];
  int tid = threadIdx.x;
  int lane = tid & 63, wv = tid >> 6;
  int ml = lane & 15, quad = lane >> 4;
  int wr = wv & 1, wc = wv >> 1;        // wave tile: 32 rows x 64 cols
  int m0 = blockIdx.x * 64, n0 = blockIdx.y * 128;
  f4 acc[2][4] = {};
  for (int k0 = 0; k0 < K; k0 += 32) {
    {
      int c = tid;                      // A: 256 chunks
      int row = c >> 2, kc = (c & 3) * 8;
      glds16(&As[c * 8], A + (size_t)(m0 + row) * K + k0 + kc);
    }
#pragma unroll
    for (int it = 0; it < 2; it++) {    // B: 512 chunks
      int c = it * 256 + tid;
      int row = c >> 2, kc = (c & 3) * 8;
      glds16(&Bs[c * 8], W + (size_t)(n0 + row) * K + k0 + kc);
    }
    __syncthreads();
    bf8 af[2], bfr[4];
#pragma unroll
    for (int mi = 0; mi < 2; mi++)
      af[mi] = ld8(&As[(wr * 32 + mi * 16 + ml) * 32 + quad * 8]);
#pragma unroll
    for (int ni = 0; ni < 4; ni++)
      bfr[ni] = ld8(&Bs[(wc * 64 + ni * 16 + ml) * 32 + quad * 8]);
#pragma unroll
    for (int mi = 0; mi < 2; mi++)
#pragma unroll
      for (int ni = 0; ni < 4; ni++)
        acc[mi][ni] = MFMA(af[mi], bfr[ni], acc[mi][ni]);
    __syncthreads();
  }
#pragma unroll
  for (int mi = 0; mi < 2; mi++)
#pragma unroll
    for (int ni = 0; ni < 4; ni++)
#pragma unroll
      for (int r = 0; r < 4; r++) {
        int row = m0 + wr * 32 + mi * 16 + quad * 4 + r;
        int col = n0 + wc * 64 + ni * 16 + ml;
        size_t idx = (size_t)row * N + col;
        float v = acc[mi][ni][r] + bias[col];
        if (EPI == 1) v = 0.5f * v * (1.0f + erff(v * 0.70710678118654752f));
        if (EPI == 2) v += res[idx];
        if (ODT == 1) ((bf16*)outp)[idx] = f2b(v);
        else ((float*)outp)[idx] = v;
      }
}

// ---------------- V transpose: VT[b,h,d,s] = qkv[b,s,2D + h*64 + d] --------
__global__ __launch_bounds__(256) void vtrans(const bf16* __restrict__ qkv,
                                              bf16* __restrict__ VT) {
  int bid = blockIdx.x;
  int st = bid % (SS / 64);
  int h = (bid / (SS / 64)) % NHEAD;
  int b = bid / ((SS / 64) * NHEAD);
  __shared__ bf16 tile[64][65];
  int s0 = st * 64;
  int tid = threadIdx.x;
  for (int it = 0; it < 16; it++) {
    int sl = it * 4 + (tid >> 6), dl = tid & 63;
    tile[sl][dl] = qkv[(size_t)(b * SS + s0 + sl) * (3 * DDIM) + 2 * DDIM + h * 64 + dl];
  }
  __syncthreads();
  for (int it = 0; it < 16; it++) {
    int dl = it * 4 + (tid >> 6), sl = tid & 63;
    VT[((size_t)(b * NHEAD + h) * 64 + dl) * SS + s0 + sl] = tile[sl][dl];
  }
}

// ---- Flash attention v7: block-shared LDS K/V staging + fused antithetic
// phases. All 4 waves share (b,h) and identical tile ranges (nkt = blk+1 and
// 32-blk are block-uniform) -> stage each K/V tile ONCE per block; each wave
// updates both its phase-0 and phase-1 subtile states from the shared tile.
// K/V staged via glds16 with XOR-swizzled SOURCE mapping (dest lane-linear as
// HW requires) so ds_read_b128 fragments spread across all bank groups.
__device__ __forceinline__ void phase_tile(int kt, int q0, int nkt,
                                           const bf8* qf, f4* oacc,
                                           float* m_r, float* l_r,
                                           const bf16* __restrict__ Ks,
                                           const bf16* __restrict__ Vs,
                                           bf16 (*pl)[72], int ml, int quad) {
  if (kt >= nkt) return;                 // block-uniform condition
  const float SC = 0.125f * 1.44269504089f;  // 1/sqrt(64) * log2(e)
  int k0 = kt * 64;
  f4 sacc[4] = {{0,0,0,0},{0,0,0,0},{0,0,0,0},{0,0,0,0}};
#pragma unroll
  for (int kk = 0; kk < 2; kk++)
#pragma unroll
    for (int c = 0; c < 4; c++) {
      int chunk = ((c * 16 + ml) << 3) + ((kk * 4 + quad) ^ (ml & 7));
      bf8 kf = ld8(&Ks[chunk * 8]);
      sacc[c] = MFMA(qf[kk], kf, sacc[c]);
    }
  float sv[4][4];
#pragma unroll
  for (int c = 0; c < 4; c++)
#pragma unroll
    for (int r = 0; r < 4; r++) sv[c][r] = sacc[c][r] * SC;
  if (kt == nkt - 1) {                   // diagonal tile: causal mask
#pragma unroll
    for (int c = 0; c < 4; c++)
#pragma unroll
      for (int r = 0; r < 4; r++) {
        int qi = q0 + quad * 4 + r;
        int kj = k0 + c * 16 + ml;
        if (kj > qi) sv[c][r] = -1e9f;
      }
  }
  float alpha[4];
#pragma unroll
  for (int r = 0; r < 4; r++) {
    float mx = fmaxf(fmaxf(sv[0][r], sv[1][r]), fmaxf(sv[2][r], sv[3][r]));
#pragma unroll
    for (int off = 1; off < 16; off <<= 1) mx = fmaxf(mx, __shfl_xor(mx, off));
    float mn = fmaxf(m_r[r], mx);
    float rs = 0.0f;
#pragma unroll
    for (int c = 0; c < 4; c++) {
      float p = fexp2(sv[c][r] - mn);
      sv[c][r] = p;
      rs += p;
    }
#pragma unroll
    for (int off = 1; off < 16; off <<= 1) rs += __shfl_xor(rs, off);
    alpha[r] = fexp2(m_r[r] - mn);
    l_r[r] = l_r[r] * alpha[r] + rs;
    m_r[r] = mn;
  }
#pragma unroll
  for (int c = 0; c < 4; c++)
#pragma unroll
    for (int r = 0; r < 4; r++) oacc[c][r] *= alpha[r];
  // C-layout -> A-layout via per-wave LDS slice (padded to 72: conflict-free,
  // 144 B row stride keeps 16 B alignment)
#pragma unroll
  for (int c = 0; c < 4; c++)
#pragma unroll
    for (int r = 0; r < 4; r++)
      pl[quad * 4 + r][c * 16 + ml] = f2b(sv[c][r]);
  bf8 pf[2];
#pragma unroll
  for (int kk = 0; kk < 2; kk++) pf[kk] = ld8(&pl[ml][kk * 32 + quad * 8]);
#pragma unroll
  for (int c = 0; c < 4; c++)
#pragma unroll
    for (int kk = 0; kk < 2; kk++) {
      int chunk = ((c * 16 + ml) << 3) + ((kk * 4 + quad) ^ (ml & 7));
      bf8 vf = ld8(&Vs[chunk * 8]);
      oacc[c] = MFMA(pf[kk], vf, oacc[c]);
    }
}

__global__ __launch_bounds__(256) void flash_attn(const bf16* __restrict__ qkv,
                                                  const bf16* __restrict__ VT,
                                                  bf16* __restrict__ obuf) {
  int bid = blockIdx.x;                 // grid: BB*NHEAD*16 = 512 blocks
  int blk = bid & 15;
  int h = (bid >> 4) & 15;
  int b = bid >> 8;
  int tid = threadIdx.x;
  int wv = tid >> 6, lane = tid & 63;
  int ml = lane & 15, quad = lane >> 4;
  int idx0 = blk * 4 + wv;              // phase-0 subtile (16 Q rows)
  int idx1 = 127 - idx0;                // phase-1 (antithetic)
  int q0a = idx0 * 16, q0b = idx1 * 16;
  int nkt0 = blk + 1;                   // block-uniform (idx0>>2 == blk)
  int nkt1 = 32 - blk;                  // block-uniform; nkt1 >= nkt0
  int maxn = nkt1;

  __shared__ __align__(16) bf16 Ks[64 * 64];
  __shared__ __align__(16) bf16 Vs[64 * 64];
  __shared__ __align__(16) bf16 plds[4][16][72];
  bf16 (*pl)[72] = plds[wv];

  bf8 qfa[2], qfb[2];
#pragma unroll
  for (int kk = 0; kk < 2; kk++) {
    qfa[kk] = ld8(qkv + (size_t)(b * SS + q0a + ml) * (3 * DDIM) + h * 64 + kk * 32 + quad * 8);
    qfb[kk] = ld8(qkv + (size_t)(b * SS + q0b + ml) * (3 * DDIM) + h * 64 + kk * 32 + quad * 8);
  }
  f4 oacca[4] = {{0,0,0,0},{0,0,0,0},{0,0,0,0},{0,0,0,0}};
  f4 oaccb[4] = {{0,0,0,0},{0,0,0,0},{0,0,0,0},{0,0,0,0}};
  float ma[4], la[4], mb[4], lb[4];
#pragma unroll
  for (int r = 0; r < 4; r++) {
    ma[r] = -1e30f; la[r] = 0.0f;
    mb[r] = -1e30f; lb[r] = 0.0f;
  }

  const bf16* kglob = qkv + (size_t)b * SS * (3 * DDIM) + DDIM + h * 64;
  const bf16* vglob = VT + (size_t)(b * NHEAD + h) * 64 * SS;

  for (int kt = 0; kt < maxn; kt++) {
    int k0 = kt * 64;
    // stage K tile (64 seq x 64 hd) and V^T tile (64 hd x 64 seq), swizzled:
    // LDS chunk lam holds logical chunk (row=lam>>3, ch=(lam&7)^(row&7))
#pragma unroll
    for (int it = 0; it < 2; it++) {
      int lam = it * 256 + tid;
      int row = lam >> 3;
      int ch = (lam & 7) ^ (row & 7);
      glds16(&Ks[lam * 8], kglob + (size_t)(k0 + row) * (3 * DDIM) + ch * 8);
      glds16(&Vs[lam * 8], vglob + (size_t)row * SS + k0 + ch * 8);
    }
    __syncthreads();
    phase_tile(kt, q0a, nkt0, qfa, oacca, ma, la, Ks, Vs, pl, ml, quad);
    phase_tile(kt, q0b, nkt1, qfb, oaccb, mb, lb, Ks, Vs, pl, ml, quad);
    __syncthreads();
  }
#pragma unroll
  for (int c = 0; c < 4; c++)
#pragma unroll
    for (int r = 0; r < 4; r++) {
      int rowa = q0a + quad * 4 + r;
      int rowb = q0b + quad * 4 + r;
      obuf[(size_t)(b * SS + rowa) * DDIM + h * 64 + c * 16 + ml] =
          f2b(oacca[c][r] / la[r]);
      obuf[(size_t)(b * SS + rowb) * DDIM + h * 64 + c * 16 + ml] =
          f2b(oaccb[c][r] / lb[r]);
    }
}

// ---------------- final: out = y + P0 + P1 + b2 + mhc(XD) ----------------
__global__ __launch_bounds__(256) void final_k(const float* __restrict__ y,
                                               const float* __restrict__ P0,
                                               const float* __restrict__ P1,
                                               const float* __restrict__ bias,
                                               const float* __restrict__ xd,
                                               const float* __restrict__ hres,
                                               const float* __restrict__ gres,
                                               float* __restrict__ out) {
  int row = blockIdx.x;  // [B*S]
  int b = row / SS;
  int tid = threadIdx.x;
  __shared__ float cf[8][8];
  if (tid < 64) cf[tid >> 3][tid & 7] = hres[tid] * gres[b * NSTR + (tid & 7)];
  __syncthreads();
  const float* yr = y + (size_t)row * DDIM;
  const float* p0 = P0 + (size_t)row * DDIM;
  const float* p1 = P1 + (size_t)row * DDIM;
  const float* xr = xd + (size_t)row * DDIM;
  float* o = out + (size_t)row * DDIM;
  for (int i = tid; i < DDIM; i += 256) {
    int m = i >> 7, dd = i & 127;
    float acc = yr[i] + p0[i] + p1[i] + bias[i];
#pragma unroll
    for (int n = 0; n < 8; n++) acc += cf[m][n] * xr[n * SDIMC + dd];
    o[i] = acc;
  }
}

extern "C" void kernel_launch(void* const* d_in, const int* in_sizes, int n_in,
                              void* d_out, int out_size, void* d_ws, size_t ws_size,
                              hipStream_t stream) {
  const float* x     = (const float*)d_in[0];
  const float* decay = (const float*)d_in[3];
  const float* gw    = (const float*)d_in[4];
  const float* gb    = (const float*)d_in[5];
  const float* phi   = (const float*)d_in[6];
  const float* ln1   = (const float*)d_in[7];
  const float* ln2   = (const float*)d_in[8];
  const float* w1    = (const float*)d_in[9];
  const float* b1    = (const float*)d_in[10];
  const float* w2    = (const float*)d_in[11];
  const float* b2    = (const float*)d_in[12];
  const float* ipw   = (const float*)d_in[13];
  const float* ipb   = (const float*)d_in[14];
  const float* ow    = (const float*)d_in[15];
  const float* obs   = (const float*)d_in[16];
  float* out = (float*)d_out;

  // ---- workspace layout (105 MB total) ----
  const size_t MB = 1048576ull;
  char* wsp = (char*)d_ws;
  float* SA   = (float*)(wsp);                 // 128 KB  chunk states / sums
  float* SIN  = (float*)(wsp + 131072ull);     // 128 KB  incoming states
  float* GRES = (float*)(wsp + 262144ull);     // 64 B
  float* HRES = (float*)(wsp + 262208ull);     // 256 B
  float* XD   = (float*)(wsp + 1 * MB);        // 16 MB   x_delta (f32), live to end
  float* AO   = (float*)(wsp + 17 * MB);       // 16 MB   y = x_delta + attn_out
  bf16*  NORM = (bf16*)(wsp + 33 * MB);        // 8 MB    normed/normed2 (dead after ffn1)
  bf16*  OB   = (bf16*)(wsp + 41 * MB);        // 8 MB    attn out (dead after outproj)
  bf16*  QKV  = (bf16*)(wsp + 49 * MB);        // 24 MB   (dead after flash)
  bf16*  VT   = (bf16*)(wsp + 73 * MB);        // 8 MB    (dead after flash)
  bf16*  HB   = (bf16*)(wsp + 49 * MB);        // 32 MB   gelu hidden, ALIASES QKV+VT
  bf16*  WIPW = (bf16*)(wsp + 81 * MB);        // 6 MB    in_proj_w bf16 (dead after qkv)
  bf16*  WOW  = (bf16*)(wsp + 87 * MB);        // 2 MB    out_w bf16 (dead after outproj)
  bf16*  W1B  = (bf16*)(wsp + 89 * MB);        // 8 MB    w1 bf16 (dead after ffn1)
  bf16*  W2B  = (bf16*)(wsp + 97 * MB);        // 8 MB    w2 bf16 (live thru ffn2)
  // ffn2 split-K partials (f32, 16 MB each), live from ffn2 thru final_k:
  // PK0 over NORM+OB (33-49 MB, dead), PK1 over WIPW/WOW/W1B (81-97 MB, dead)
  float* PK0  = (float*)(wsp + 33 * MB);
  float* PK1  = (float*)(wsp + 81 * MB);

  // 0: convert all GEMM weights f32 -> bf16 (single launch, float4)
  cvt_all<<<dim3(12 * DDIM * DDIM / 1024), dim3(256), 0, stream>>>(
      ipw, ow, w1, w2, WIPW, WOW, W1B, W2B);

  // 1-3: delta operator scan
  delta_passA<<<dim3(BB * NCH * DDIM / 256), dim3(256), 0, stream>>>(x, decay, SA);
  delta_passB<<<dim3(BB * DDIM / 256), dim3(256), 0, stream>>>(SA, decay, SIN);
  delta_passC<<<dim3(BB * NCH * DDIM / 256), dim3(256), 0, stream>>>(x, decay, SIN, XD, SA);
  // 4: gates + sinkhorn
  gates_sinkhorn<<<dim3(1), dim3(1024), 0, stream>>>(SA, gw, gb, phi, GRES, HRES);
  // 5: rmsnorm1 (XD -> NORM)
  rmsnorm_k<<<dim3(BB * SS), dim3(256), 0, stream>>>(XD, ln1, NORM);
  // 6: qkv = NORM @ in_proj_w.T + in_proj_b   [4096 x 3072]
  gemm_lds<1, 0><<<dim3(32, 24), dim3(256), 0, stream>>>(NORM, WIPW, ipb, nullptr,
                                                         QKV, BB * SS, 3 * DDIM, DDIM);
  // 7: V transpose
  vtrans<<<dim3(BB * NHEAD * (SS / 64)), dim3(256), 0, stream>>>(QKV, VT);
  // 8: flash attention -> OB (block-shared LDS K/V, fused antithetic phases)
  flash_attn<<<dim3(BB * NHEAD * 16), dim3(256), 0, stream>>>(QKV, VT, OB);
  // 9: out-proj + residual(XD) -> AO (= y)
  gemm_lds64<0, 2><<<dim3(64, 8), dim3(256), 0, stream>>>(OB, WOW, obs, XD,
                                                          AO, BB * SS, DDIM, DDIM);
  // 10: rmsnorm2 (AO -> NORM)
  rmsnorm_k<<<dim3(BB * SS), dim3(256), 0, stream>>>(AO, ln2, NORM);
  // 11: ffn1 + gelu -> HB   [4096 x 4096]  (HB aliases dead QKV/VT)
  gemm_lds<1, 1><<<dim3(32, 32), dim3(256), 0, stream>>>(NORM, W1B, b1, nullptr,
                                                         HB, BB * SS, 4 * DDIM, DDIM);
  // 12: ffn2 split-K=2, ONE launch (512 co-resident blocks) -> PK0/PK1
  gemm_part2<<<dim3(32, 8, 2), dim3(256), 0, stream>>>(HB, W2B, PK0, PK1,
                                                       BB * SS, DDIM, 2 * DDIM, 4 * DDIM);
  // 13: final out = y + PK0 + PK1 + b2 + mhc(XD)  (ffn2 epilogue fused here)
  final_k<<<dim3(BB * SS), dim3(256), 0, stream>>>(AO, PK0, PK1, b2, XD,
                                                   HRES, GRES, out);
}